// Round 19
// baseline (1156.889 us; speedup 1.0000x reference)
//
#include <hip/hip_runtime.h>
#include <stdint.h>

#define NN 100000
#define RR 4
#define EE 1600000
#define DD 128
#define TN 32
#define BLK 256
#define NB 98     // ceil(NN/1024) 1024-node buckets
#define CHUNK 2048

typedef unsigned int u32;
typedef unsigned short u16;

__device__ __forceinline__ u16 f2bf(float f) {
  union { float f; u32 i; } c; c.f = f;
  const u32 lsb = (c.i >> 16) & 1u;
  c.i += 0x7fffu + lsb;  // round-to-nearest-even
  return (u16)(c.i >> 16);
}
__device__ __forceinline__ u32 pack2(float a, float b) {
  return (u32)f2bf(a) | ((u32)f2bf(b) << 16);
}
__device__ __forceinline__ float u2f(u32 u) {
  union { u32 i; float f; } c; c.i = u; return c.f;
}

// ---------- pass 1: per-chunk LDS bucket histogram -> global bucket counts ----------
__global__ __launch_bounds__(256)
void k_cnt(const int* __restrict__ dst, int* __restrict__ cnt) {
  const int r = blockIdx.y;
  const long base = (long)blockIdx.x * CHUNK;
  const int t = threadIdx.x;
  __shared__ int hist[NB];
  for (int i = t; i < NB; i += 256) hist[i] = 0;
  __syncthreads();
#pragma unroll
  for (int k = 0; k < 8; ++k) {
    const long e = base + k * 256 + t;
    if (e < EE) atomicAdd(&hist[dst[(size_t)r * EE + e] >> 10], 1);
  }
  __syncthreads();
  if (t < NB && hist[t]) atomicAdd(&cnt[r * NB + t], hist[t]);
}

// ---------- pass 2: scan 4x98 bucket counts -> bucket bases + bin cursors ----------
__global__ __launch_bounds__(512)
void k_bscan(const int* __restrict__ cnt, int* __restrict__ bOff, int* __restrict__ gcur) {
  __shared__ int tmp[512];
  const int t = threadIdx.x;
  const int r = t >> 7, b = t & 127;
  const int v = (b < NB) ? cnt[r * NB + b] : 0;
  tmp[t] = v;
  __syncthreads();
  for (int o = 1; o < 128; o <<= 1) {
    const int y = (b >= o) ? tmp[t - o] : 0;
    __syncthreads();
    tmp[t] += y;
    __syncthreads();
  }
  if (b < NB) {
    const int excl = tmp[t] - v;
    bOff[r * (NB + 1) + b] = excl;
    gcur[r * NB + b] = excl;
    if (b == NB - 1) bOff[r * (NB + 1) + NB] = tmp[t];
  }
}

// ---------- pass 3: coarse binning with LDS-staged dense writes ----------
__global__ __launch_bounds__(256)
void k_bin(const int* __restrict__ src, const int* __restrict__ dst,
           int* __restrict__ gcur, int2* __restrict__ pairs) {
  const int r = blockIdx.y;
  const long base = (long)blockIdx.x * CHUNK;
  const int t = threadIdx.x;
  __shared__ int hist[NB], lofs[NB], gbase[NB], hcur[NB];
  __shared__ int2 stage[CHUNK];  // 16 KB
  for (int i = t; i < NB; i += 256) hist[i] = 0;
  __syncthreads();
  int d[8], s[8];
#pragma unroll
  for (int k = 0; k < 8; ++k) {
    const long e = base + k * 256 + t;
    if (e < EE) {
      d[k] = dst[(size_t)r * EE + e];
      s[k] = src[(size_t)r * EE + e];
      atomicAdd(&hist[d[k] >> 10], 1);
    } else d[k] = -1;
  }
  __syncthreads();
  if (t == 0) {
    int run = 0;
    for (int b = 0; b < NB; ++b) { lofs[b] = run; run += hist[b]; }
  }
  __syncthreads();
  if (t < NB) {
    hcur[t] = 0;
    gbase[t] = hist[t] ? atomicAdd(&gcur[r * NB + t], hist[t]) : 0;
  }
  __syncthreads();
#pragma unroll
  for (int k = 0; k < 8; ++k) {
    if (d[k] >= 0) {
      const int b = d[k] >> 10;
      const int slot = lofs[b] + atomicAdd(&hcur[b], 1);
      stage[slot] = make_int2(d[k], s[k]);
    }
  }
  __syncthreads();
  const int total = (int)((EE - base < CHUNK) ? (EE - base) : CHUNK);
  for (int i = t; i < total; i += 256) {
    const int2 p = stage[i];
    const int b = p.x >> 10;
    pairs[(size_t)r * EE + gbase[b] + (i - lofs[b])] = p;
  }
}

// ---------- pass 4: in-bucket CSR build + placement, all LDS atomics ----------
__global__ __launch_bounds__(256)
void k_place(const int2* __restrict__ pairs, const int* __restrict__ bOff,
             int* __restrict__ off, int* __restrict__ sorted) {
  const int r = blockIdx.y;
  const int b = blockIdx.x;
  const int nlo = b << 10;
  const int span0 = bOff[r * (NB + 1) + b];
  const int span1 = bOff[r * (NB + 1) + b + 1];
  const int t = threadIdx.x;
  __shared__ __align__(16) int ncnt[1024];
  __shared__ int part[256];
  ((int4*)ncnt)[t] = make_int4(0, 0, 0, 0);
  __syncthreads();
  for (int i = span0 + t; i < span1; i += 256)
    atomicAdd(&ncnt[pairs[(size_t)r * EE + i].x - nlo], 1);
  __syncthreads();
  const int4 c = ((int4*)ncnt)[t];
  const int s = c.x + c.y + c.z + c.w;
  part[t] = s;
  __syncthreads();
  for (int o = 1; o < 256; o <<= 1) {
    const int y = (t >= o) ? part[t - o] : 0;
    __syncthreads();
    part[t] += y;
    __syncthreads();
  }
  const int base = part[t] - s;
  int ex[4];
  ex[0] = base;
  ex[1] = base + c.x;
  ex[2] = base + c.x + c.y;
  ex[3] = base + c.x + c.y + c.z;
  ((int4*)ncnt)[t] = make_int4(ex[0], ex[1], ex[2], ex[3]);
#pragma unroll
  for (int j = 0; j < 4; ++j) {
    const int n = nlo + t * 4 + j;
    if (n < NN) off[(size_t)r * (NN + 1) + n] = span0 + ex[j];
  }
  if (b == NB - 1 && t == 0) off[(size_t)r * (NN + 1) + NN] = span1;
  __syncthreads();
  for (int i = span0 + t; i < span1; i += 256) {
    const int2 p = pairs[(size_t)r * EE + i];
    const int pos = atomicAdd(&ncnt[p.x - nlo], 1);
    sorted[(size_t)r * EE + span0 + pos] = p.y;
  }
}

// ---------- convert ALL relations' features to packed bf16 rows ----------
__global__ __launch_bounds__(256)
void k_cvt(const float* __restrict__ nf, u32* __restrict__ nf16) {
  const int r = blockIdx.y;
  const long t = (long)blockIdx.x * 256 + threadIdx.x;
  if (t >= (long)NN * 64) return;
  const int n = (int)(t >> 6);
  const int l = (int)(t & 63);
  const float2 v = *(const float2*)(nf + ((size_t)n * RR + r) * DD + l * 2);
  nf16[(size_t)r * NN * 64 + t] = pack2(v.x, v.y);
}

// ---------- pre-convert weights to packed bf16 (row-major pairs) ----------
// w16 layout: [mat][8192] u32 pairs; mat 0=W1, 1=W2, 2..5=Ws1[r]
__global__ __launch_bounds__(256)
void k_wcvt(const float* __restrict__ W1, const float* __restrict__ W2,
            const float* __restrict__ Ws1, u32* __restrict__ w16) {
  const int i = blockIdx.x * 256 + threadIdx.x;
  if (i >= 6 * 8192) return;
  const int m = i >> 13;
  const int p = i & 8191;
  const float* srcm = (m == 0) ? W1 : (m == 1) ? W2 : Ws1 + (size_t)(m - 2) * DD * DD;
  const float2 v = *(const float2*)(srcm + (size_t)p * 2);
  w16[i] = pack2(v.x, v.y);
}

// ---- 4x4-blocked full-K gemm, bf16-packed weights read from L1/L2 ----
// W element reuse (8x per block) is served by L1; no LDS staging, no barriers
// inside the GEMM -> compiler software-pipelines the global W loads.
__device__ __forceinline__ void gemm4x4g(const float (*__restrict__ in)[DD],
                                         const u32* __restrict__ Wg,
                                         int rg, int c2, float acc[4][4]) {
  for (int k4 = 0; k4 < DD; k4 += 4) {
    const float4 a0 = *(const float4*)(&in[rg + 0][k4]);
    const float4 a1 = *(const float4*)(&in[rg + 1][k4]);
    const float4 a2 = *(const float4*)(&in[rg + 2][k4]);
    const float4 a3 = *(const float4*)(&in[rg + 3][k4]);
    const uint2 p0 = *(const uint2*)(&Wg[(k4 + 0) * 64 + c2]);
    const uint2 p1 = *(const uint2*)(&Wg[(k4 + 1) * 64 + c2]);
    const uint2 p2 = *(const uint2*)(&Wg[(k4 + 2) * 64 + c2]);
    const uint2 p3 = *(const uint2*)(&Wg[(k4 + 3) * 64 + c2]);
    const float4 w0 = make_float4(u2f(p0.x << 16), u2f(p0.x & 0xffff0000u),
                                  u2f(p0.y << 16), u2f(p0.y & 0xffff0000u));
    const float4 w1 = make_float4(u2f(p1.x << 16), u2f(p1.x & 0xffff0000u),
                                  u2f(p1.y << 16), u2f(p1.y & 0xffff0000u));
    const float4 w2 = make_float4(u2f(p2.x << 16), u2f(p2.x & 0xffff0000u),
                                  u2f(p2.y << 16), u2f(p2.y & 0xffff0000u));
    const float4 w3 = make_float4(u2f(p3.x << 16), u2f(p3.x & 0xffff0000u),
                                  u2f(p3.y << 16), u2f(p3.y & 0xffff0000u));
#define ROWF(i, ai)                                                                               \
    acc[i][0] = fmaf(ai.x, w0.x, fmaf(ai.y, w1.x, fmaf(ai.z, w2.x, fmaf(ai.w, w3.x, acc[i][0])))); \
    acc[i][1] = fmaf(ai.x, w0.y, fmaf(ai.y, w1.y, fmaf(ai.z, w2.y, fmaf(ai.w, w3.y, acc[i][1])))); \
    acc[i][2] = fmaf(ai.x, w0.z, fmaf(ai.y, w1.z, fmaf(ai.z, w2.z, fmaf(ai.w, w3.z, acc[i][2])))); \
    acc[i][3] = fmaf(ai.x, w0.w, fmaf(ai.y, w1.w, fmaf(ai.z, w2.w, fmaf(ai.w, w3.w, acc[i][3]))));
    ROWF(0, a0) ROWF(1, a1) ROWF(2, a2) ROWF(3, a3)
#undef ROWF
  }
}

// ------- fused: bf16 gather(CSR, 2-row interleaved) + MLP + LN + scores -------
// grid = (3125, RR). LDS = 18 KB -> 8 blocks/CU (32 waves, 100% wave occupancy).
__global__ __launch_bounds__(BLK, 8)
void k_mlp(const float* __restrict__ nf, const u32* __restrict__ nf16all,
           const u32* __restrict__ w16, const float* __restrict__ b1,
           const float* __restrict__ b2, const float* __restrict__ Ws2,
           const float* __restrict__ gamma, const float* __restrict__ beta,
           const int* __restrict__ off, const int* __restrict__ sortedSrc,
           float* __restrict__ S, float* __restrict__ out) {
  __shared__ float sA[TN][DD];     // 16 KB
  __shared__ float sWs2s[512];     //  2 KB (scores weights)

  const int tid = threadIdx.x;
  const int r = blockIdx.y;
  const int n0 = blockIdx.x * TN;
  const int rg = (tid >> 5) * 4;   // 8 row groups of 4
  const int c4 = (tid & 31) * 4;   // 32 col groups of 4
  const int c2 = c4 >> 1;          // u32-pair column index

  const u32* Wg1 = w16;
  const u32* Wg2 = w16 + 8192;
  const u32* Wg3 = w16 + (size_t)(2 + r) * 8192;
  const u32* nf16 = nf16all + (size_t)r * NN * 64;

  // ---- stage rst = feat(f32) + bf16-gather(CSR) -> sA ----
  // 2-row interleave: 8+8 loads in flight.
  {
    const int wv = tid >> 6;
    const int lane = tid & 63;
    const int* ss = sortedSrc + (size_t)r * EE;
    const int* offr = off + (size_t)r * (NN + 1);
#pragma unroll
    for (int qp = 0; qp < 4; ++qp) {
      const int i0 = wv * 8 + qp * 2;
      const int i1 = i0 + 1;
      const int na = n0 + i0, nb = n0 + i1;   // always < NN (NN % TN == 0)
      float2 a0 = *(const float2*)(nf + ((size_t)na * RR + r) * DD + lane * 2);
      float2 a1 = *(const float2*)(nf + ((size_t)nb * RR + r) * DD + lane * 2);
      int e0 = offr[na], E0 = offr[na + 1];
      int e1 = offr[nb], E1 = offr[nb + 1];
      while (e0 + 8 <= E0 && e1 + 8 <= E1) {
        u32 v0[8], v1[8];
#pragma unroll
        for (int k = 0; k < 8; ++k) v0[k] = nf16[((size_t)ss[e0 + k] << 6) + lane];
#pragma unroll
        for (int k = 0; k < 8; ++k) v1[k] = nf16[((size_t)ss[e1 + k] << 6) + lane];
#pragma unroll
        for (int k = 0; k < 8; ++k) {
          a0.x += u2f(v0[k] << 16);
          a0.y += u2f(v0[k] & 0xffff0000u);
        }
#pragma unroll
        for (int k = 0; k < 8; ++k) {
          a1.x += u2f(v1[k] << 16);
          a1.y += u2f(v1[k] & 0xffff0000u);
        }
        e0 += 8; e1 += 8;
      }
      for (; e0 + 8 <= E0; e0 += 8) {
        u32 v[8];
#pragma unroll
        for (int k = 0; k < 8; ++k) v[k] = nf16[((size_t)ss[e0 + k] << 6) + lane];
#pragma unroll
        for (int k = 0; k < 8; ++k) {
          a0.x += u2f(v[k] << 16);
          a0.y += u2f(v[k] & 0xffff0000u);
        }
      }
      for (; e0 < E0; ++e0) {
        const u32 v = nf16[((size_t)ss[e0] << 6) + lane];
        a0.x += u2f(v << 16);
        a0.y += u2f(v & 0xffff0000u);
      }
      for (; e1 + 8 <= E1; e1 += 8) {
        u32 v[8];
#pragma unroll
        for (int k = 0; k < 8; ++k) v[k] = nf16[((size_t)ss[e1 + k] << 6) + lane];
#pragma unroll
        for (int k = 0; k < 8; ++k) {
          a1.x += u2f(v[k] << 16);
          a1.y += u2f(v[k] & 0xffff0000u);
        }
      }
      for (; e1 < E1; ++e1) {
        const u32 v = nf16[((size_t)ss[e1] << 6) + lane];
        a1.x += u2f(v << 16);
        a1.y += u2f(v & 0xffff0000u);
      }
      *(float2*)(&sA[i0][lane * 2]) = a0;
      *(float2*)(&sA[i1][lane * 2]) = a1;
    }
  }
  __syncthreads();

  float acc[4][4];

  // ---- GEMM1 + bias + relu ----
#pragma unroll
  for (int i = 0; i < 4; ++i)
#pragma unroll
    for (int jj = 0; jj < 4; ++jj) acc[i][jj] = 0.f;
  gemm4x4g(sA, Wg1, rg, c2, acc);
  __syncthreads();
  {
    const float4 bb = *(const float4*)(&b1[c4]);
#pragma unroll
    for (int i = 0; i < 4; ++i)
      *(float4*)(&sA[rg + i][c4]) = make_float4(
          fmaxf(acc[i][0] + bb.x, 0.f), fmaxf(acc[i][1] + bb.y, 0.f),
          fmaxf(acc[i][2] + bb.z, 0.f), fmaxf(acc[i][3] + bb.w, 0.f));
  }
  __syncthreads();

  // ---- GEMM2 + bias + relu ----
#pragma unroll
  for (int i = 0; i < 4; ++i)
#pragma unroll
    for (int jj = 0; jj < 4; ++jj) acc[i][jj] = 0.f;
  gemm4x4g(sA, Wg2, rg, c2, acc);
  __syncthreads();
  {
    const float4 bb = *(const float4*)(&b2[c4]);
#pragma unroll
    for (int i = 0; i < 4; ++i)
      *(float4*)(&sA[rg + i][c4]) = make_float4(
          fmaxf(acc[i][0] + bb.x, 0.f), fmaxf(acc[i][1] + bb.y, 0.f),
          fmaxf(acc[i][2] + bb.z, 0.f), fmaxf(acc[i][3] + bb.w, 0.f));
  }
  __syncthreads();

  // ---- LayerNorm (8 threads/row, stats in registers via shfl) ----
  {
    const int i = tid >> 3;          // 0..31
    const int c0 = (tid & 7) * 16;
    float s = 0.f, s2 = 0.f;
    float hv[16];
#pragma unroll
    for (int c = 0; c < 16; ++c) {
      const float v = sA[i][c0 + c];
      hv[c] = v;
      s += v; s2 += v * v;
    }
#pragma unroll
    for (int off2 = 1; off2 < 8; off2 <<= 1) {
      s  += __shfl_xor(s, off2);
      s2 += __shfl_xor(s2, off2);
    }
    const float mu = s * (1.f / 128.f);
    const float var = fmaxf(s2 * (1.f / 128.f) - mu * mu, 0.f);
    const float rs = rsqrtf(var + 1e-5f);
    const int n = n0 + i;
#pragma unroll
    for (int c = 0; c < 16; ++c) {
      hv[c] = (hv[c] - mu) * rs * gamma[c0 + c] + beta[c0 + c];
      sA[i][c0 + c] = hv[c];   // own slice only: no cross-thread hazard
    }
    if (n < NN) {
      float4* op = (float4*)(out + ((size_t)n * RR + r) * DD + c0);
#pragma unroll
      for (int q = 0; q < 4; ++q)
        op[q] = make_float4(hv[q * 4], hv[q * 4 + 1], hv[q * 4 + 2], hv[q * 4 + 3]);
    }
  }
  __syncthreads();

  // ---- GEMM3: tanh(h @ Ws1[r]) ----
#pragma unroll
  for (int i = 0; i < 4; ++i)
#pragma unroll
    for (int jj = 0; jj < 4; ++jj) acc[i][jj] = 0.f;
  gemm4x4g(sA, Wg3, rg, c2, acc);
  __syncthreads();
#pragma unroll
  for (int i = 0; i < 4; ++i)
    *(float4*)(&sA[rg + i][c4]) = make_float4(
        tanhf(acc[i][0]), tanhf(acc[i][1]), tanhf(acc[i][2]), tanhf(acc[i][3]));
  {
    sWs2s[tid]       = Ws2[(size_t)r * 512 + tid];
    sWs2s[tid + 256] = Ws2[(size_t)r * 512 + tid + 256];
  }
  __syncthreads();

  // ---- scores = tanh(...) @ Ws2[r] -> S ----
  if (tid < TN * 4) {
    const int i = tid >> 2;
    const int k = tid & 3;
    float a = 0.f;
#pragma unroll 8
    for (int q = 0; q < DD; ++q) a = fmaf(sA[i][q], sWs2s[q * 4 + k], a);
    const int n = n0 + i;
    if (n < NN) S[((size_t)r * NN + n) * 4 + k] = a;
  }
}

// -------- softmax over relations + final mix (in place on out) --------
__global__ __launch_bounds__(256)
void k_combine(const float* __restrict__ S, float* __restrict__ out) {
  const long gw = (((long)blockIdx.x * 256) + threadIdx.x) >> 6;
  const int lane = threadIdx.x & 63;
  if (gw >= NN) return;
  const int n = (int)gw;
  float a[4][4];
#pragma unroll
  for (int r = 0; r < 4; ++r)
#pragma unroll
    for (int k = 0; k < 4; ++k)
      a[r][k] = S[((size_t)r * NN + n) * 4 + k];
#pragma unroll
  for (int k = 0; k < 4; ++k) {
    const float m = fmaxf(fmaxf(a[0][k], a[1][k]), fmaxf(a[2][k], a[3][k]));
    const float e0 = expf(a[0][k] - m);
    const float e1 = expf(a[1][k] - m);
    const float e2 = expf(a[2][k] - m);
    const float e3 = expf(a[3][k] - m);
    const float inv = 1.f / (e0 + e1 + e2 + e3);
    a[0][k] = e0 * inv; a[1][k] = e1 * inv; a[2][k] = e2 * inv; a[3][k] = e3 * inv;
  }
  float2 hv[4];
#pragma unroll
  for (int k = 0; k < 4; ++k)
    hv[k] = *(const float2*)(out + ((size_t)n * RR + k) * DD + lane * 2);
#pragma unroll
  for (int r = 0; r < 4; ++r) {
    float2 o;
    o.x = a[r][0] * hv[0].x + a[r][1] * hv[1].x + a[r][2] * hv[2].x + a[r][3] * hv[3].x;
    o.y = a[r][0] * hv[0].y + a[r][1] * hv[1].y + a[r][2] * hv[2].y + a[r][3] * hv[3].y;
    *(float2*)(out + ((size_t)n * RR + r) * DD + lane * 2) = o;
  }
}

extern "C" void kernel_launch(void* const* d_in, const int* in_sizes, int n_in,
                              void* d_out, int out_size, void* d_ws, size_t ws_size,
                              hipStream_t stream) {
  const float* nf    = (const float*)d_in[0];
  const int*   src   = (const int*)d_in[1];
  const int*   dst   = (const int*)d_in[2];
  const float* W1    = (const float*)d_in[3];
  const float* b1    = (const float*)d_in[4];
  const float* W2    = (const float*)d_in[5];
  const float* b2    = (const float*)d_in[6];
  const float* Ws1   = (const float*)d_in[7];
  const float* Ws2   = (const float*)d_in[8];
  const float* gamma = (const float*)d_in[9];
  const float* beta  = (const float*)d_in[10];
  float* out = (float*)d_out;

  // ws layout (~136 MB; ws proven >= 211 MB in round 5):
  float* S      = (float*)d_ws;
  int*   off    = (int*)(S + (size_t)RR * NN * 4);
  int*   cnt    = off + (size_t)RR * (NN + 1);
  int*   bOff   = cnt + (size_t)RR * NB;
  int*   gcur   = bOff + (size_t)RR * (NB + 1);
  u32*   w16    = (u32*)(gcur + (size_t)RR * NB);
  int*   sorted = (int*)(w16 + (size_t)6 * 8192);
  int2*  pairs  = (int2*)(sorted + (size_t)RR * EE);
  u32*   nf16   = (u32*)pairs;   // alias: valid only after k_place

  hipMemsetAsync(cnt, 0, (size_t)RR * NB * sizeof(int), stream);
  k_wcvt<<<dim3(192), dim3(256), 0, stream>>>(W1, W2, Ws1, w16);
  {
    dim3 grid((EE + CHUNK - 1) / CHUNK, RR);
    k_cnt<<<grid, dim3(256), 0, stream>>>(dst, cnt);
  }
  k_bscan<<<dim3(1), dim3(512), 0, stream>>>(cnt, bOff, gcur);
  {
    dim3 grid((EE + CHUNK - 1) / CHUNK, RR);
    k_bin<<<grid, dim3(256), 0, stream>>>(src, dst, gcur, pairs);
  }
  k_place<<<dim3(NB, RR), dim3(256), 0, stream>>>(pairs, bOff, off, sorted);
  {
    dim3 grid((unsigned)(((long)NN * 64 + 255) / 256), RR);
    k_cvt<<<grid, dim3(256), 0, stream>>>(nf, nf16);
  }
  {
    dim3 grid((NN + TN - 1) / TN, RR);   // single merged launch, all relations
    k_mlp<<<grid, dim3(BLK), 0, stream>>>(nf, nf16, w16, b1, b2, Ws2,
                                          gamma, beta, off, sorted, S, out);
  }
  {
    const long blocks = ((long)NN + 3) / 4;  // 1 wave/node
    k_combine<<<dim3((unsigned)blocks), dim3(256), 0, stream>>>(S, out);
  }
}

// Round 20
// 920.819 us; speedup vs baseline: 1.2564x; 1.2564x over previous
//
#include <hip/hip_runtime.h>
#include <stdint.h>

#define NN 100000
#define RR 4
#define EE 1600000
#define DD 128
#define TN 32
#define BLK 256
#define NB 98     // ceil(NN/1024) 1024-node buckets
#define CHUNK 2048

typedef unsigned int u32;
typedef unsigned short u16;
typedef _Float16 h2v __attribute__((ext_vector_type(2)));

__device__ __forceinline__ u16 f2bf(float f) {
  union { float f; u32 i; } c; c.f = f;
  const u32 lsb = (c.i >> 16) & 1u;
  c.i += 0x7fffu + lsb;  // round-to-nearest-even
  return (u16)(c.i >> 16);
}
__device__ __forceinline__ u32 pack2(float a, float b) {
  return (u32)f2bf(a) | ((u32)f2bf(b) << 16);
}
__device__ __forceinline__ float u2f(u32 u) {
  union { u32 i; float f; } c; c.i = u; return c.f;
}
__device__ __forceinline__ u32 packh2(float x, float y) {
  union { h2v h; u32 u; } c;
  c.h = h2v{(_Float16)x, (_Float16)y};
  return c.u;
}
__device__ __forceinline__ float2 unph2(u32 v) {
  union { u32 u; h2v h; } c; c.u = v;
  return make_float2((float)c.h.x, (float)c.h.y);
}
__device__ __forceinline__ float fdot2u(u32 a, u32 b, float c) {
  union { u32 u; h2v h; } A, B;
  A.u = a; B.u = b;
  return __builtin_amdgcn_fdot2(A.h, B.h, c, false);
}

// ---------- pass 1: per-chunk LDS bucket histogram -> global bucket counts ----------
__global__ __launch_bounds__(256)
void k_cnt(const int* __restrict__ dst, int* __restrict__ cnt) {
  const int r = blockIdx.y;
  const long base = (long)blockIdx.x * CHUNK;
  const int t = threadIdx.x;
  __shared__ int hist[NB];
  for (int i = t; i < NB; i += 256) hist[i] = 0;
  __syncthreads();
#pragma unroll
  for (int k = 0; k < 8; ++k) {
    const long e = base + k * 256 + t;
    if (e < EE) atomicAdd(&hist[dst[(size_t)r * EE + e] >> 10], 1);
  }
  __syncthreads();
  if (t < NB && hist[t]) atomicAdd(&cnt[r * NB + t], hist[t]);
}

// ---------- pass 2: scan 4x98 bucket counts -> bucket bases + bin cursors ----------
__global__ __launch_bounds__(512)
void k_bscan(const int* __restrict__ cnt, int* __restrict__ bOff, int* __restrict__ gcur) {
  __shared__ int tmp[512];
  const int t = threadIdx.x;
  const int r = t >> 7, b = t & 127;
  const int v = (b < NB) ? cnt[r * NB + b] : 0;
  tmp[t] = v;
  __syncthreads();
  for (int o = 1; o < 128; o <<= 1) {
    const int y = (b >= o) ? tmp[t - o] : 0;
    __syncthreads();
    tmp[t] += y;
    __syncthreads();
  }
  if (b < NB) {
    const int excl = tmp[t] - v;
    bOff[r * (NB + 1) + b] = excl;
    gcur[r * NB + b] = excl;
    if (b == NB - 1) bOff[r * (NB + 1) + NB] = tmp[t];
  }
}

// ---------- pass 3: coarse binning with LDS-staged dense writes ----------
__global__ __launch_bounds__(256)
void k_bin(const int* __restrict__ src, const int* __restrict__ dst,
           int* __restrict__ gcur, int2* __restrict__ pairs) {
  const int r = blockIdx.y;
  const long base = (long)blockIdx.x * CHUNK;
  const int t = threadIdx.x;
  __shared__ int hist[NB], lofs[NB], gbase[NB], hcur[NB];
  __shared__ int2 stage[CHUNK];  // 16 KB
  for (int i = t; i < NB; i += 256) hist[i] = 0;
  __syncthreads();
  int d[8], s[8];
#pragma unroll
  for (int k = 0; k < 8; ++k) {
    const long e = base + k * 256 + t;
    if (e < EE) {
      d[k] = dst[(size_t)r * EE + e];
      s[k] = src[(size_t)r * EE + e];
      atomicAdd(&hist[d[k] >> 10], 1);
    } else d[k] = -1;
  }
  __syncthreads();
  if (t == 0) {
    int run = 0;
    for (int b = 0; b < NB; ++b) { lofs[b] = run; run += hist[b]; }
  }
  __syncthreads();
  if (t < NB) {
    hcur[t] = 0;
    gbase[t] = hist[t] ? atomicAdd(&gcur[r * NB + t], hist[t]) : 0;
  }
  __syncthreads();
#pragma unroll
  for (int k = 0; k < 8; ++k) {
    if (d[k] >= 0) {
      const int b = d[k] >> 10;
      const int slot = lofs[b] + atomicAdd(&hcur[b], 1);
      stage[slot] = make_int2(d[k], s[k]);
    }
  }
  __syncthreads();
  const int total = (int)((EE - base < CHUNK) ? (EE - base) : CHUNK);
  for (int i = t; i < total; i += 256) {
    const int2 p = stage[i];
    const int b = p.x >> 10;
    pairs[(size_t)r * EE + gbase[b] + (i - lofs[b])] = p;
  }
}

// ---------- pass 4: in-bucket CSR build + placement, all LDS atomics ----------
__global__ __launch_bounds__(256)
void k_place(const int2* __restrict__ pairs, const int* __restrict__ bOff,
             int* __restrict__ off, int* __restrict__ sorted) {
  const int r = blockIdx.y;
  const int b = blockIdx.x;
  const int nlo = b << 10;
  const int span0 = bOff[r * (NB + 1) + b];
  const int span1 = bOff[r * (NB + 1) + b + 1];
  const int t = threadIdx.x;
  __shared__ __align__(16) int ncnt[1024];
  __shared__ int part[256];
  ((int4*)ncnt)[t] = make_int4(0, 0, 0, 0);
  __syncthreads();
  for (int i = span0 + t; i < span1; i += 256)
    atomicAdd(&ncnt[pairs[(size_t)r * EE + i].x - nlo], 1);
  __syncthreads();
  const int4 c = ((int4*)ncnt)[t];
  const int s = c.x + c.y + c.z + c.w;
  part[t] = s;
  __syncthreads();
  for (int o = 1; o < 256; o <<= 1) {
    const int y = (t >= o) ? part[t - o] : 0;
    __syncthreads();
    part[t] += y;
    __syncthreads();
  }
  const int base = part[t] - s;
  int ex[4];
  ex[0] = base;
  ex[1] = base + c.x;
  ex[2] = base + c.x + c.y;
  ex[3] = base + c.x + c.y + c.z;
  ((int4*)ncnt)[t] = make_int4(ex[0], ex[1], ex[2], ex[3]);
#pragma unroll
  for (int j = 0; j < 4; ++j) {
    const int n = nlo + t * 4 + j;
    if (n < NN) off[(size_t)r * (NN + 1) + n] = span0 + ex[j];
  }
  if (b == NB - 1 && t == 0) off[(size_t)r * (NN + 1) + NN] = span1;
  __syncthreads();
  for (int i = span0 + t; i < span1; i += 256) {
    const int2 p = pairs[(size_t)r * EE + i];
    const int pos = atomicAdd(&ncnt[p.x - nlo], 1);
    sorted[(size_t)r * EE + span0 + pos] = p.y;
  }
}

// ---------- convert ALL relations' features to packed bf16 rows ----------
__global__ __launch_bounds__(256)
void k_cvt(const float* __restrict__ nf, u32* __restrict__ nf16) {
  const int r = blockIdx.y;
  const long t = (long)blockIdx.x * 256 + threadIdx.x;
  if (t >= (long)NN * 64) return;
  const int n = (int)(t >> 6);
  const int l = (int)(t & 63);
  const float2 v = *(const float2*)(nf + ((size_t)n * RR + r) * DD + l * 2);
  nf16[(size_t)r * NN * 64 + t] = pack2(v.x, v.y);
}

// ---------- pre-convert weights to f16 K-pairs, [mat][kk*128+col] ----------
// w16k[m][kk*128+col] = half2{ W[2kk][col], W[2kk+1][col] }; m 0=W1,1=W2,2..5=Ws1[r]
__global__ __launch_bounds__(256)
void k_wcvt(const float* __restrict__ W1, const float* __restrict__ W2,
            const float* __restrict__ Ws1, u32* __restrict__ w16k) {
  const int i = blockIdx.x * 256 + threadIdx.x;
  if (i >= 6 * 8192) return;
  const int m = i >> 13;
  const int p = i & 8191;
  const int kk = p >> 7, col = p & 127;
  const float* srcm = (m == 0) ? W1 : (m == 1) ? W2 : Ws1 + (size_t)(m - 2) * DD * DD;
  w16k[i] = packh2(srcm[(size_t)(2 * kk) * DD + col], srcm[(size_t)(2 * kk + 1) * DD + col]);
}

// ---- one 32x128x128 GEMM accumulate via v_dot2_f32_f16 ----
// sA16[row][kp] = half2 of dims {2kp, 2kp+1}. W staged in 16 KB halves.
__device__ __forceinline__ void gemm_dot2(const u32* __restrict__ Wg,
                                          u32 (*__restrict__ sA16)[64],
                                          u32* __restrict__ sWd,
                                          int tid, int rg, int c4, float acc[4][4]) {
#pragma unroll
  for (int i = 0; i < 4; ++i)
#pragma unroll
    for (int j = 0; j < 4; ++j) acc[i][j] = 0.f;
#pragma unroll
  for (int h = 0; h < 2; ++h) {
    __syncthreads();                    // prev sWd reads done / sA16 writes visible
    {
      const uint4* s4 = (const uint4*)(Wg + h * 4096);
      uint4* d4 = (uint4*)sWd;
#pragma unroll
      for (int k = 0; k < 4; ++k) d4[tid + k * 256] = s4[tid + k * 256];
    }
    __syncthreads();
#pragma unroll 8
    for (int kk = 0; kk < 32; ++kk) {
      const int kp = h * 32 + kk;
      const u32 a0 = sA16[rg + 0][kp];
      const u32 a1 = sA16[rg + 1][kp];
      const u32 a2 = sA16[rg + 2][kp];
      const u32 a3 = sA16[rg + 3][kp];
      const uint4 w = *(const uint4*)(sWd + kk * 128 + c4);
      acc[0][0] = fdot2u(a0, w.x, acc[0][0]);
      acc[0][1] = fdot2u(a0, w.y, acc[0][1]);
      acc[0][2] = fdot2u(a0, w.z, acc[0][2]);
      acc[0][3] = fdot2u(a0, w.w, acc[0][3]);
      acc[1][0] = fdot2u(a1, w.x, acc[1][0]);
      acc[1][1] = fdot2u(a1, w.y, acc[1][1]);
      acc[1][2] = fdot2u(a1, w.z, acc[1][2]);
      acc[1][3] = fdot2u(a1, w.w, acc[1][3]);
      acc[2][0] = fdot2u(a2, w.x, acc[2][0]);
      acc[2][1] = fdot2u(a2, w.y, acc[2][1]);
      acc[2][2] = fdot2u(a2, w.z, acc[2][2]);
      acc[2][3] = fdot2u(a2, w.w, acc[2][3]);
      acc[3][0] = fdot2u(a3, w.x, acc[3][0]);
      acc[3][1] = fdot2u(a3, w.y, acc[3][1]);
      acc[3][2] = fdot2u(a3, w.z, acc[3][2]);
      acc[3][3] = fdot2u(a3, w.w, acc[3][3]);
    }
  }
  __syncthreads();                      // all sA16 reads done before writeback
}

// ------- fused: bf16 gather(CSR, 2-row interleaved) + f16-dot2 MLP + LN + scores -------
// grid = (3125, RR). LDS = 26 KB -> 6 blocks/CU.
__global__ __launch_bounds__(BLK, 6)
void k_mlp(const float* __restrict__ nf, const u32* __restrict__ nf16all,
           const u32* __restrict__ w16k, const float* __restrict__ b1,
           const float* __restrict__ b2, const float* __restrict__ Ws2,
           const float* __restrict__ gamma, const float* __restrict__ beta,
           const int* __restrict__ off, const int* __restrict__ sortedSrc,
           float* __restrict__ S, float* __restrict__ out) {
  __shared__ u32 sA16[TN][64];                 //  8 KB packed f16 activations
  __shared__ __align__(16) u32 sWd[32 * 128];  // 16 KB staged W half (k-pairs x cols)
  __shared__ float sWs2s[512];                 //  2 KB

  const int tid = threadIdx.x;
  const int r = blockIdx.y;
  const int n0 = blockIdx.x * TN;
  const int rg = (tid >> 5) * 4;   // 8 row groups of 4
  const int c4 = (tid & 31) * 4;   // 32 col groups of 4

  const u32* Wg1 = w16k;
  const u32* Wg2 = w16k + 8192;
  const u32* Wg3 = w16k + (size_t)(2 + r) * 8192;
  const u32* nf16 = nf16all + (size_t)r * NN * 64;

  // ---- stage rst = feat(f32) + bf16-gather(CSR) -> sA16 (packed f16) ----
  // 2-row interleave: 8+8 loads in flight.
  {
    const int wv = tid >> 6;
    const int lane = tid & 63;
    const int* ss = sortedSrc + (size_t)r * EE;
    const int* offr = off + (size_t)r * (NN + 1);
#pragma unroll
    for (int qp = 0; qp < 4; ++qp) {
      const int i0 = wv * 8 + qp * 2;
      const int i1 = i0 + 1;
      const int na = n0 + i0, nb = n0 + i1;   // always < NN (NN % TN == 0)
      float2 a0 = *(const float2*)(nf + ((size_t)na * RR + r) * DD + lane * 2);
      float2 a1 = *(const float2*)(nf + ((size_t)nb * RR + r) * DD + lane * 2);
      int e0 = offr[na], E0 = offr[na + 1];
      int e1 = offr[nb], E1 = offr[nb + 1];
      while (e0 + 8 <= E0 && e1 + 8 <= E1) {
        u32 v0[8], v1[8];
#pragma unroll
        for (int k = 0; k < 8; ++k) v0[k] = nf16[((size_t)ss[e0 + k] << 6) + lane];
#pragma unroll
        for (int k = 0; k < 8; ++k) v1[k] = nf16[((size_t)ss[e1 + k] << 6) + lane];
#pragma unroll
        for (int k = 0; k < 8; ++k) {
          a0.x += u2f(v0[k] << 16);
          a0.y += u2f(v0[k] & 0xffff0000u);
        }
#pragma unroll
        for (int k = 0; k < 8; ++k) {
          a1.x += u2f(v1[k] << 16);
          a1.y += u2f(v1[k] & 0xffff0000u);
        }
        e0 += 8; e1 += 8;
      }
      for (; e0 + 8 <= E0; e0 += 8) {
        u32 v[8];
#pragma unroll
        for (int k = 0; k < 8; ++k) v[k] = nf16[((size_t)ss[e0 + k] << 6) + lane];
#pragma unroll
        for (int k = 0; k < 8; ++k) {
          a0.x += u2f(v[k] << 16);
          a0.y += u2f(v[k] & 0xffff0000u);
        }
      }
      for (; e0 < E0; ++e0) {
        const u32 v = nf16[((size_t)ss[e0] << 6) + lane];
        a0.x += u2f(v << 16);
        a0.y += u2f(v & 0xffff0000u);
      }
      for (; e1 + 8 <= E1; e1 += 8) {
        u32 v[8];
#pragma unroll
        for (int k = 0; k < 8; ++k) v[k] = nf16[((size_t)ss[e1 + k] << 6) + lane];
#pragma unroll
        for (int k = 0; k < 8; ++k) {
          a1.x += u2f(v[k] << 16);
          a1.y += u2f(v[k] & 0xffff0000u);
        }
      }
      for (; e1 < E1; ++e1) {
        const u32 v = nf16[((size_t)ss[e1] << 6) + lane];
        a1.x += u2f(v << 16);
        a1.y += u2f(v & 0xffff0000u);
      }
      sA16[i0][lane] = packh2(a0.x, a0.y);
      sA16[i1][lane] = packh2(a1.x, a1.y);
    }
  }
  // gemm_dot2's first internal sync makes sA16 visible

  float acc[4][4];

  // ---- GEMM1 + bias + relu ----
  gemm_dot2(Wg1, sA16, sWd, tid, rg, c4, acc);
  {
    const float4 bb = *(const float4*)(&b1[c4]);
#pragma unroll
    for (int i = 0; i < 4; ++i) {
      const float v0 = fmaxf(acc[i][0] + bb.x, 0.f);
      const float v1 = fmaxf(acc[i][1] + bb.y, 0.f);
      const float v2 = fmaxf(acc[i][2] + bb.z, 0.f);
      const float v3 = fmaxf(acc[i][3] + bb.w, 0.f);
      sA16[rg + i][(c4 >> 1)]     = packh2(v0, v1);
      sA16[rg + i][(c4 >> 1) + 1] = packh2(v2, v3);
    }
  }

  // ---- GEMM2 + bias + relu ----
  gemm_dot2(Wg2, sA16, sWd, tid, rg, c4, acc);
  {
    const float4 bb = *(const float4*)(&b2[c4]);
#pragma unroll
    for (int i = 0; i < 4; ++i) {
      const float v0 = fmaxf(acc[i][0] + bb.x, 0.f);
      const float v1 = fmaxf(acc[i][1] + bb.y, 0.f);
      const float v2 = fmaxf(acc[i][2] + bb.z, 0.f);
      const float v3 = fmaxf(acc[i][3] + bb.w, 0.f);
      sA16[rg + i][(c4 >> 1)]     = packh2(v0, v1);
      sA16[rg + i][(c4 >> 1) + 1] = packh2(v2, v3);
    }
  }
  __syncthreads();

  // ---- LayerNorm (8 threads/row, stats in registers via shfl) ----
  {
    const int i = tid >> 3;          // 0..31
    const int c0 = (tid & 7) * 16;
    float s = 0.f, s2 = 0.f;
    float hv[16];
#pragma unroll
    for (int q = 0; q < 8; ++q) {
      const float2 v = unph2(sA16[i][(c0 >> 1) + q]);
      hv[2 * q] = v.x; hv[2 * q + 1] = v.y;
      s += v.x + v.y;
      s2 += v.x * v.x + v.y * v.y;
    }
#pragma unroll
    for (int o = 1; o < 8; o <<= 1) {
      s  += __shfl_xor(s, o);
      s2 += __shfl_xor(s2, o);
    }
    const float mu = s * (1.f / 128.f);
    const float var = fmaxf(s2 * (1.f / 128.f) - mu * mu, 0.f);
    const float rs = rsqrtf(var + 1e-5f);
    const int n = n0 + i;
#pragma unroll
    for (int c = 0; c < 16; ++c)
      hv[c] = (hv[c] - mu) * rs * gamma[c0 + c] + beta[c0 + c];
#pragma unroll
    for (int q = 0; q < 8; ++q)
      sA16[i][(c0 >> 1) + q] = packh2(hv[2 * q], hv[2 * q + 1]);
    if (n < NN) {
      float4* op = (float4*)(out + ((size_t)n * RR + r) * DD + c0);
#pragma unroll
      for (int q = 0; q < 4; ++q)
        op[q] = make_float4(hv[q * 4], hv[q * 4 + 1], hv[q * 4 + 2], hv[q * 4 + 3]);
    }
  }
  // GEMM3's first internal sync covers LN's sA16 writes

  // ---- GEMM3: tanh(h @ Ws1[r]) ----
  gemm_dot2(Wg3, sA16, sWd, tid, rg, c4, acc);
#pragma unroll
  for (int i = 0; i < 4; ++i) {
    sA16[rg + i][(c4 >> 1)]     = packh2(tanhf(acc[i][0]), tanhf(acc[i][1]));
    sA16[rg + i][(c4 >> 1) + 1] = packh2(tanhf(acc[i][2]), tanhf(acc[i][3]));
  }
  {
    sWs2s[tid]       = Ws2[(size_t)r * 512 + tid];
    sWs2s[tid + 256] = Ws2[(size_t)r * 512 + tid + 256];
  }
  __syncthreads();

  // ---- scores = tanh(...) @ Ws2[r] -> S ----
  if (tid < TN * 4) {
    const int i = tid >> 2;
    const int k = tid & 3;
    float a = 0.f;
#pragma unroll 8
    for (int q = 0; q < 64; ++q) {
      const float2 v = unph2(sA16[i][q]);
      a = fmaf(v.x, sWs2s[(2 * q) * 4 + k], a);
      a = fmaf(v.y, sWs2s[(2 * q + 1) * 4 + k], a);
    }
    const int n = n0 + i;
    if (n < NN) S[((size_t)r * NN + n) * 4 + k] = a;
  }
}

// -------- softmax over relations + final mix (in place on out) --------
__global__ __launch_bounds__(256)
void k_combine(const float* __restrict__ S, float* __restrict__ out) {
  const long gw = (((long)blockIdx.x * 256) + threadIdx.x) >> 6;
  const int lane = threadIdx.x & 63;
  if (gw >= NN) return;
  const int n = (int)gw;
  float a[4][4];
#pragma unroll
  for (int r = 0; r < 4; ++r)
#pragma unroll
    for (int k = 0; k < 4; ++k)
      a[r][k] = S[((size_t)r * NN + n) * 4 + k];
#pragma unroll
  for (int k = 0; k < 4; ++k) {
    const float m = fmaxf(fmaxf(a[0][k], a[1][k]), fmaxf(a[2][k], a[3][k]));
    const float e0 = expf(a[0][k] - m);
    const float e1 = expf(a[1][k] - m);
    const float e2 = expf(a[2][k] - m);
    const float e3 = expf(a[3][k] - m);
    const float inv = 1.f / (e0 + e1 + e2 + e3);
    a[0][k] = e0 * inv; a[1][k] = e1 * inv; a[2][k] = e2 * inv; a[3][k] = e3 * inv;
  }
  float2 hv[4];
#pragma unroll
  for (int k = 0; k < 4; ++k)
    hv[k] = *(const float2*)(out + ((size_t)n * RR + k) * DD + lane * 2);
#pragma unroll
  for (int r = 0; r < 4; ++r) {
    float2 o;
    o.x = a[r][0] * hv[0].x + a[r][1] * hv[1].x + a[r][2] * hv[2].x + a[r][3] * hv[3].x;
    o.y = a[r][0] * hv[0].y + a[r][1] * hv[1].y + a[r][2] * hv[2].y + a[r][3] * hv[3].y;
    *(float2*)(out + ((size_t)n * RR + r) * DD + lane * 2) = o;
  }
}

extern "C" void kernel_launch(void* const* d_in, const int* in_sizes, int n_in,
                              void* d_out, int out_size, void* d_ws, size_t ws_size,
                              hipStream_t stream) {
  const float* nf    = (const float*)d_in[0];
  const int*   src   = (const int*)d_in[1];
  const int*   dst   = (const int*)d_in[2];
  const float* W1    = (const float*)d_in[3];
  const float* b1    = (const float*)d_in[4];
  const float* W2    = (const float*)d_in[5];
  const float* b2    = (const float*)d_in[6];
  const float* Ws1   = (const float*)d_in[7];
  const float* Ws2   = (const float*)d_in[8];
  const float* gamma = (const float*)d_in[9];
  const float* beta  = (const float*)d_in[10];
  float* out = (float*)d_out;

  // ws layout (~136 MB; ws proven >= 211 MB in round 5):
  float* S      = (float*)d_ws;
  int*   off    = (int*)(S + (size_t)RR * NN * 4);
  int*   cnt    = off + (size_t)RR * (NN + 1);
  int*   bOff   = cnt + (size_t)RR * NB;
  int*   gcur   = bOff + (size_t)RR * (NB + 1);
  u32*   w16k   = (u32*)(gcur + (size_t)RR * NB);
  int*   sorted = (int*)(w16k + (size_t)6 * 8192);
  int2*  pairs  = (int2*)(sorted + (size_t)RR * EE);
  u32*   nf16   = (u32*)pairs;   // alias: valid only after k_place

  hipMemsetAsync(cnt, 0, (size_t)RR * NB * sizeof(int), stream);
  k_wcvt<<<dim3(192), dim3(256), 0, stream>>>(W1, W2, Ws1, w16k);
  {
    dim3 grid((EE + CHUNK - 1) / CHUNK, RR);
    k_cnt<<<grid, dim3(256), 0, stream>>>(dst, cnt);
  }
  k_bscan<<<dim3(1), dim3(512), 0, stream>>>(cnt, bOff, gcur);
  {
    dim3 grid((EE + CHUNK - 1) / CHUNK, RR);
    k_bin<<<grid, dim3(256), 0, stream>>>(src, dst, gcur, pairs);
  }
  k_place<<<dim3(NB, RR), dim3(256), 0, stream>>>(pairs, bOff, off, sorted);
  {
    dim3 grid((unsigned)(((long)NN * 64 + 255) / 256), RR);
    k_cvt<<<grid, dim3(256), 0, stream>>>(nf, nf16);
  }
  {
    dim3 grid((NN + TN - 1) / TN, RR);   // single merged launch, all relations
    k_mlp<<<grid, dim3(BLK), 0, stream>>>(nf, nf16, w16k, b1, b2, Ws2,
                                          gamma, beta, off, sorted, S, out);
  }
  {
    const long blocks = ((long)NN + 3) / 4;  // 1 wave/node
    k_combine<<<dim3((unsigned)blocks), dim3(256), 0, stream>>>(S, out);
  }
}